// Round 4
// baseline (674.625 us; speedup 1.0000x reference)
//
#include <hip/hip_runtime.h>
#include <math.h>

#define Bz 4
#define Tz 2048
#define Cz 1024
#define Hz 16
#define Dz 64
#define MTOK (Bz*Tz)   // 8192

typedef __attribute__((ext_vector_type(8))) short short8;
typedef __attribute__((ext_vector_type(4))) short short4v;
typedef __attribute__((ext_vector_type(4))) float f32x4;
typedef __attribute__((ext_vector_type(16))) float f32x16;

typedef unsigned int u32_g __attribute__((address_space(1)));
typedef unsigned int u32_l __attribute__((address_space(3)));

__device__ __forceinline__ unsigned short f2bf(float f) {
    unsigned int u = __float_as_uint(f);
    u += 0x7fffu + ((u >> 16) & 1u);
    return (unsigned short)(u >> 16);
}
__device__ __forceinline__ float bf2f(unsigned short h) {
    return __uint_as_float((unsigned int)h << 16);
}

__device__ __forceinline__ void async_cp16(const unsigned short* g, unsigned short* l) {
    __builtin_amdgcn_global_load_lds((const u32_g*)g, (u32_l*)l, 16, 0, 0);
}

// ---------------- weight transpose: W[K][N] f32 -> Wt[N][K] bf16 ----------------
__global__ void transpose_w(const float* __restrict__ W, unsigned short* __restrict__ Wt,
                            int K, int N) {
    __shared__ float tile[32][33];
    int n0 = blockIdx.x * 32, k0 = blockIdx.y * 32;
    int tx = threadIdx.x, ty = threadIdx.y;   // (32, 8)
    #pragma unroll
    for (int i = 0; i < 4; i++)
        tile[ty + i * 8][tx] = W[(size_t)(k0 + ty + i * 8) * N + n0 + tx];
    __syncthreads();
    #pragma unroll
    for (int i = 0; i < 4; i++)
        Wt[(size_t)(n0 + ty + i * 8) * K + k0 + tx] = f2bf(tile[tx][ty + i * 8]);
}

// ---------------- layernorm: fp32 in -> bf16 out ----------------
__global__ void ln_kernel(const float* __restrict__ x, const float* __restrict__ g,
                          const float* __restrict__ bb, unsigned short* __restrict__ out) {
    int tok = blockIdx.x, tid = threadIdx.x;
    const float4 v = ((const float4*)(x + (size_t)tok * Cz))[tid];
    float s = v.x + v.y + v.z + v.w;
    float sq = v.x * v.x + v.y * v.y + v.z * v.z + v.w * v.w;
    #pragma unroll
    for (int m = 1; m < 64; m <<= 1) { s += __shfl_xor(s, m); sq += __shfl_xor(sq, m); }
    __shared__ float red[8];
    int lane = tid & 63, wid = tid >> 6;
    if (!lane) { red[wid] = s; red[4 + wid] = sq; }
    __syncthreads();
    s = red[0] + red[1] + red[2] + red[3];
    sq = red[4] + red[5] + red[6] + red[7];
    float mu = s * (1.0f / Cz);
    float var = sq * (1.0f / Cz) - mu * mu;
    float rs = rsqrtf(var + 1e-5f);
    float4 gv = ((const float4*)g)[tid];
    float4 bv = ((const float4*)bb)[tid];
    short4v o;
    o[0] = f2bf((v.x - mu) * rs * gv.x + bv.x);
    o[1] = f2bf((v.y - mu) * rs * gv.y + bv.y);
    o[2] = f2bf((v.z - mu) * rs * gv.z + bv.z);
    o[3] = f2bf((v.w - mu) * rs * gv.w + bv.w);
    *(short4v*)(out + (size_t)tok * Cz + tid * 4) = o;
}

// ---------------- GEMM: C = A[M,ld] @ Bt[N,ld]^T over Kloop, 32x32x16 MFMA ----------------
#define MODE_QKV 0
#define MODE_RESID 1
#define MODE_GELU 2
#define MODE_PARTIAL 3

template <int MODE>
__launch_bounds__(256)
__global__ void gemm_bt(const unsigned short* __restrict__ A, const unsigned short* __restrict__ Bt,
                        int ld, int Kloop, int N, const float* __restrict__ bias,
                        float* __restrict__ outf, unsigned short* __restrict__ outb,
                        const float* __restrict__ resid,
                        unsigned short* __restrict__ qo, unsigned short* __restrict__ ko,
                        unsigned short* __restrict__ vo) {
    __shared__ __align__(16) unsigned short As[128 * 32];
    __shared__ __align__(16) unsigned short Bs[128 * 32];
    const int tid = threadIdx.x;
    const int lane = tid & 63;
    const int l31 = lane & 31, half = lane >> 5;
    const int wid = tid >> 6;
    const int m0 = blockIdx.y * 128, n0 = blockIdx.x * 128;
    const int wm = (wid >> 1) * 64, wn = (wid & 1) * 64;

    const unsigned short* Ap = A + (size_t)blockIdx.z * Kloop;
    const unsigned short* Bp = Bt + (size_t)blockIdx.z * Kloop;

    f32x16 acc[2][2] = {};
    const int rowa = tid >> 2, cola = (tid & 3) * 8;
    const unsigned short* Ag0 = Ap + (size_t)(m0 + rowa) * ld + cola;
    const unsigned short* Ag1 = Ag0 + (size_t)64 * ld;
    const unsigned short* Bg0 = Bp + (size_t)(n0 + rowa) * ld + cola;
    const unsigned short* Bg1 = Bg0 + (size_t)64 * ld;
    unsigned short* lA0 = &As[tid * 8]; unsigned short* lA1 = &As[2048 + tid * 8];
    unsigned short* lB0 = &Bs[tid * 8]; unsigned short* lB1 = &Bs[2048 + tid * 8];

    for (int k0 = 0; k0 < Kloop; k0 += 32) {
        async_cp16(Ag0 + k0, lA0);
        async_cp16(Ag1 + k0, lA1);
        async_cp16(Bg0 + k0, lB0);
        async_cp16(Bg1 + k0, lB1);
        __syncthreads();
        short8 af[2][2], bfr[2][2];
        #pragma unroll
        for (int mi = 0; mi < 2; mi++)
            #pragma unroll
            for (int ks = 0; ks < 2; ks++)
                af[mi][ks] = *(const short8*)&As[(wm + mi * 32 + l31) * 32 + ks * 16 + half * 8];
        #pragma unroll
        for (int ni = 0; ni < 2; ni++)
            #pragma unroll
            for (int ks = 0; ks < 2; ks++)
                bfr[ni][ks] = *(const short8*)&Bs[(wn + ni * 32 + l31) * 32 + ks * 16 + half * 8];
        #pragma unroll
        for (int mi = 0; mi < 2; mi++)
            #pragma unroll
            for (int ni = 0; ni < 2; ni++)
                #pragma unroll
                for (int ks = 0; ks < 2; ks++)
                    acc[mi][ni] = __builtin_amdgcn_mfma_f32_32x32x16_bf16(af[mi][ks], bfr[ni][ks], acc[mi][ni], 0, 0, 0);
        __syncthreads();
    }

    // C/D layout (32x32): col = lane&31, row = (reg&3) + 8*(reg>>2) + 4*(lane>>5)
    #pragma unroll
    for (int ni = 0; ni < 2; ni++) {
        const int col = n0 + wn + ni * 32 + l31;
        const float bv = (MODE == MODE_PARTIAL) ? 0.f : bias[col];
        #pragma unroll
        for (int mi = 0; mi < 2; mi++) {
            #pragma unroll
            for (int r = 0; r < 16; r++) {
                const int row = m0 + wm + mi * 32 + (r & 3) + 8 * (r >> 2) + 4 * half;
                float val = acc[mi][ni][r] + bv;
                if constexpr (MODE == MODE_QKV) {
                    int which = col >> 10, cc = col & 1023;
                    int hh = cc >> 6, dd = cc & 63;
                    int b_ = row >> 11, t = row & 2047;
                    if (which == 2) {
                        vo[((size_t)(b_ * Hz + hh) * Dz + dd) * Tz + t] = f2bf(val);
                    } else {
                        unsigned short* dst = which ? ko : qo;
                        dst[((size_t)(b_ * Hz + hh) * Tz + t) * Dz + dd] = f2bf(val);
                    }
                } else if constexpr (MODE == MODE_RESID) {
                    size_t idx = (size_t)row * N + col;
                    outf[idx] = val + resid[idx];
                } else if constexpr (MODE == MODE_GELU) {
                    // tanh-form GELU: 0.5x(1+tanh(.7978845608(x+.044715x^3))) = x*sigmoid(1.5957691216(x+.044715x^3))
                    float c = val * (1.0f + 0.044715f * val * val);
                    float e = __expf(1.5957691216057308f * c);
                    float gz = val * e / (1.0f + e);
                    outb[(size_t)row * N + col] = f2bf(gz);
                } else {  // MODE_PARTIAL: bf16 partial, offset by split index
                    outb[(size_t)blockIdx.z * MTOK * N + (size_t)row * N + col] = f2bf(val);
                }
            }
        }
    }
}

// ---------------- combine split-K partials + bias + residual -> fp32 out ----------------
__global__ void combine_pr(const unsigned short* __restrict__ p, const float* __restrict__ resid,
                           const float* __restrict__ bias, float* __restrict__ out) {
    const size_t i4 = ((size_t)blockIdx.x * 256 + threadIdx.x) * 4;
    short4v a = *(const short4v*)(p + i4);
    short4v b = *(const short4v*)(p + (size_t)MTOK * Cz + i4);
    float4 rv = *(const float4*)(resid + i4);
    float4 bvv = *(const float4*)(bias + (i4 & 1023));
    float4 o;
    o.x = bf2f((unsigned short)a[0]) + bf2f((unsigned short)b[0]) + rv.x + bvv.x;
    o.y = bf2f((unsigned short)a[1]) + bf2f((unsigned short)b[1]) + rv.y + bvv.y;
    o.z = bf2f((unsigned short)a[2]) + bf2f((unsigned short)b[2]) + rv.z + bvv.z;
    o.w = bf2f((unsigned short)a[3]) + bf2f((unsigned short)b[3]) + rv.w + bvv.w;
    *(float4*)(out + i4) = o;
}

// ---------------- causal flash attention, bf16 MFMA ----------------
#define ATT_SC 0.18033688011112042f   // 0.125 * log2(e)
__launch_bounds__(256)
__global__ void attn_kernel(const unsigned short* __restrict__ qb, const unsigned short* __restrict__ kb,
                            const unsigned short* __restrict__ vt, unsigned short* __restrict__ y) {
    __shared__ __align__(16) unsigned short Klds[64 * 72];
    __shared__ __align__(16) unsigned short Vtl[64 * 72];
    __shared__ __align__(16) unsigned short Plds[4][16 * 72];
    const int tid = threadIdx.x;
    const int lane = tid & 63, wid = tid >> 6;
    const int quad = lane >> 4, l15 = lane & 15;
    const int bh = blockIdx.x & 63;
    const int qt = 15 - (int)(blockIdx.x >> 6);
    const size_t baseT = (size_t)bh * Tz;
    const size_t vbase = (size_t)bh * Dz;
    const int qb0 = qt * 128;

    short8 qf[2][2];
    {
        const unsigned short* q0p = qb + (baseT + qb0 + wid * 16 + l15) * Dz + quad * 8;
        qf[0][0] = *(const short8*)q0p;
        qf[0][1] = *(const short8*)(q0p + 32);
        const unsigned short* q1p = q0p + (size_t)64 * Dz;
        qf[1][0] = *(const short8*)q1p;
        qf[1][1] = *(const short8*)(q1p + 32);
    }

    f32x4 o[2][4] = {};
    float lsum[2][4] = {{0.f,0.f,0.f,0.f},{0.f,0.f,0.f,0.f}};

    const int krow = tid >> 3;
    const int kcol = (tid & 7) * 8;
    const int nchunk = 2 * qt + 2;

    for (int ci = 0; ci < nchunk; ci++) {
        const int k0 = ci * 64;
        *(short8*)&Klds[krow * 72 + kcol]        = *(const short8*)(kb + (baseT + k0 + krow) * Dz + kcol);
        *(short8*)&Klds[(krow + 32) * 72 + kcol] = *(const short8*)(kb + (baseT + k0 + krow + 32) * Dz + kcol);
        *(short8*)&Vtl[krow * 72 + kcol]         = *(const short8*)(vt + (vbase + krow) * Tz + k0 + kcol);
        *(short8*)&Vtl[(krow + 32) * 72 + kcol]  = *(const short8*)(vt + (vbase + krow + 32) * Tz + k0 + kcol);
        __syncthreads();

        #pragma unroll
        for (int t = 0; t < 2; t++) {
            if (t == 0 && ci == nchunk - 1) continue;
            const bool diag = (ci == nchunk - 2 + t);

            f32x4 s[4];
            #pragma unroll
            for (int c = 0; c < 4; c++) {
                short8 kf0 = *(const short8*)&Klds[(c * 16 + l15) * 72 + quad * 8];
                short8 kf1 = *(const short8*)&Klds[(c * 16 + l15) * 72 + 32 + quad * 8];
                f32x4 z = {};
                z = __builtin_amdgcn_mfma_f32_16x16x32_bf16(qf[t][0], kf0, z, 0, 0, 0);
                s[c] = __builtin_amdgcn_mfma_f32_16x16x32_bf16(qf[t][1], kf1, z, 0, 0, 0);
            }
            const int qr = qb0 + t * 64 + wid * 16 + quad * 4;
            #pragma unroll
            for (int c = 0; c < 4; c++)
                #pragma unroll
                for (int r = 0; r < 4; r++) {
                    float p = exp2f(s[c][r] * ATT_SC);
                    if (diag) {
                        int key = k0 + c * 16 + l15;
                        p = (key <= qr + r) ? p : 0.f;
                    }
                    s[c][r] = p;
                    lsum[t][r] += p;
                }
            unsigned short* P = Plds[wid];
            #pragma unroll
            for (int c = 0; c < 4; c++)
                #pragma unroll
                for (int r = 0; r < 4; r++)
                    P[(quad * 4 + r) * 72 + c * 16 + l15] = f2bf(s[c][r]);
            short8 pf0 = *(const short8*)&P[l15 * 72 + quad * 8];
            short8 pf1 = *(const short8*)&P[l15 * 72 + 32 + quad * 8];
            #pragma unroll
            for (int nc = 0; nc < 4; nc++) {
                short8 vf0 = *(const short8*)&Vtl[(nc * 16 + l15) * 72 + quad * 8];
                short8 vf1 = *(const short8*)&Vtl[(nc * 16 + l15) * 72 + 32 + quad * 8];
                o[t][nc] = __builtin_amdgcn_mfma_f32_16x16x32_bf16(pf0, vf0, o[t][nc], 0, 0, 0);
                o[t][nc] = __builtin_amdgcn_mfma_f32_16x16x32_bf16(pf1, vf1, o[t][nc], 0, 0, 0);
            }
        }
        __syncthreads();
    }

    const int b_ = bh >> 4, hh = bh & 15;
    #pragma unroll
    for (int t = 0; t < 2; t++)
        #pragma unroll
        for (int r = 0; r < 4; r++) {
            float ls = lsum[t][r];
            #pragma unroll
            for (int m = 1; m < 16; m <<= 1) ls += __shfl_xor(ls, m);
            float inv = 1.0f / ls;
            size_t tok = (size_t)qb0 + t * 64 + wid * 16 + quad * 4 + r;
            unsigned short* yr = y + ((size_t)b_ * Tz + tok) * Cz + hh * Dz;
            #pragma unroll
            for (int nc = 0; nc < 4; nc++)
                yr[nc * 16 + l15] = f2bf(o[t][nc][r] * inv);
        }
}

extern "C" void kernel_launch(void* const* d_in, const int* in_sizes, int n_in,
                              void* d_out, int out_size, void* d_ws, size_t ws_size,
                              hipStream_t stream) {
    const float* x    = (const float*)d_in[0];
    const float* ln1g = (const float*)d_in[1];
    const float* ln1b = (const float*)d_in[2];
    const float* Wqkv = (const float*)d_in[3];
    const float* bqkv = (const float*)d_in[4];
    const float* Wo   = (const float*)d_in[5];
    const float* bo   = (const float*)d_in[6];
    const float* ln2g = (const float*)d_in[7];
    const float* ln2b = (const float*)d_in[8];
    const float* Wfc  = (const float*)d_in[9];
    const float* bfc  = (const float*)d_in[10];
    const float* Wpr  = (const float*)d_in[11];
    const float* bpr  = (const float*)d_in[12];
    float* out = (float*)d_out;

    char* ws = (char*)d_ws;
    size_t off = 0;
    auto alloc = [&](size_t bytes) { void* p = ws + off; off += (bytes + 255) & ~(size_t)255; return p; };
    unsigned short* wqkv_t = (unsigned short*)alloc((size_t)3072 * 1024 * 2);
    unsigned short* wo_t   = (unsigned short*)alloc((size_t)1024 * 1024 * 2);
    unsigned short* wfc_t  = (unsigned short*)alloc((size_t)4096 * 1024 * 2);
    unsigned short* wpr_t  = (unsigned short*)alloc((size_t)1024 * 4096 * 2);
    unsigned short* h1     = (unsigned short*)alloc((size_t)MTOK * Cz * 2);
    unsigned short* qbuf   = (unsigned short*)alloc((size_t)MTOK * Cz * 2);
    unsigned short* kbuf   = (unsigned short*)alloc((size_t)MTOK * Cz * 2);
    unsigned short* vbuf   = (unsigned short*)alloc((size_t)MTOK * Cz * 2);
    unsigned short* ybuf   = (unsigned short*)alloc((size_t)MTOK * Cz * 2);
    float*          x1     = (float*)alloc((size_t)MTOK * Cz * 4);
    unsigned short* h2     = (unsigned short*)alloc((size_t)MTOK * Cz * 2);
    unsigned short* fbuf   = (unsigned short*)alloc((size_t)MTOK * 4096 * 2);
    // split-K partials (2 x 16 MB bf16) alias the dead h1+qbuf region (contiguous, both 256B-aligned)
    unsigned short* ppart  = h1;

    dim3 tb(32, 8);
    transpose_w<<<dim3(3072 / 32, 1024 / 32), tb, 0, stream>>>(Wqkv, wqkv_t, 1024, 3072);
    transpose_w<<<dim3(1024 / 32, 1024 / 32), tb, 0, stream>>>(Wo, wo_t, 1024, 1024);
    transpose_w<<<dim3(4096 / 32, 1024 / 32), tb, 0, stream>>>(Wfc, wfc_t, 1024, 4096);
    transpose_w<<<dim3(1024 / 32, 4096 / 32), tb, 0, stream>>>(Wpr, wpr_t, 4096, 1024);

    ln_kernel<<<MTOK, 256, 0, stream>>>(x, ln1g, ln1b, h1);
    gemm_bt<MODE_QKV><<<dim3(24, 64), 256, 0, stream>>>(h1, wqkv_t, 1024, 1024, 3072, bqkv,
                                                        nullptr, nullptr, nullptr, qbuf, kbuf, vbuf);
    attn_kernel<<<1024, 256, 0, stream>>>(qbuf, kbuf, vbuf, ybuf);
    gemm_bt<MODE_RESID><<<dim3(8, 64), 256, 0, stream>>>(ybuf, wo_t, 1024, 1024, 1024, bo,
                                                         x1, nullptr, x, nullptr, nullptr, nullptr);
    ln_kernel<<<MTOK, 256, 0, stream>>>(x1, ln2g, ln2b, h2);
    gemm_bt<MODE_GELU><<<dim3(32, 64), 256, 0, stream>>>(h2, wfc_t, 1024, 1024, 4096, bfc,
                                                         nullptr, fbuf, nullptr, nullptr, nullptr, nullptr);
    gemm_bt<MODE_PARTIAL><<<dim3(8, 64, 2), 256, 0, stream>>>(fbuf, wpr_t, 4096, 2048, 1024, bpr,
                                                              nullptr, ppart, nullptr, nullptr, nullptr, nullptr);
    combine_pr<<<MTOK * Cz / 1024, 256, 0, stream>>>(ppart, x1, bpr, out);
}

// Round 5
// 589.183 us; speedup vs baseline: 1.1450x; 1.1450x over previous
//
#include <hip/hip_runtime.h>
#include <math.h>

#define Bz 4
#define Tz 2048
#define Cz 1024
#define Hz 16
#define Dz 64
#define MTOK (Bz*Tz)   // 8192

typedef __attribute__((ext_vector_type(8))) short short8;
typedef __attribute__((ext_vector_type(4))) short short4v;
typedef __attribute__((ext_vector_type(4))) float f32x4;

typedef unsigned int u32_g __attribute__((address_space(1)));
typedef unsigned int u32_l __attribute__((address_space(3)));

__device__ __forceinline__ unsigned short f2bf(float f) {
    unsigned int u = __float_as_uint(f);
    u += 0x7fffu + ((u >> 16) & 1u);
    return (unsigned short)(u >> 16);
}
__device__ __forceinline__ float bf2f(unsigned short h) {
    return __uint_as_float((unsigned int)h << 16);
}

__device__ __forceinline__ void async_cp16(const unsigned short* g, unsigned short* l) {
    __builtin_amdgcn_global_load_lds((const u32_g*)g, (u32_l*)l, 16, 0, 0);
}

// ---------------- weight transpose: W[K][N] f32 -> Wt[N][K] bf16 ----------------
__global__ void transpose_w(const float* __restrict__ W, unsigned short* __restrict__ Wt,
                            int K, int N) {
    __shared__ float tile[32][33];
    int n0 = blockIdx.x * 32, k0 = blockIdx.y * 32;
    int tx = threadIdx.x, ty = threadIdx.y;   // (32, 8)
    #pragma unroll
    for (int i = 0; i < 4; i++)
        tile[ty + i * 8][tx] = W[(size_t)(k0 + ty + i * 8) * N + n0 + tx];
    __syncthreads();
    #pragma unroll
    for (int i = 0; i < 4; i++)
        Wt[(size_t)(n0 + ty + i * 8) * K + k0 + tx] = f2bf(tile[tx][ty + i * 8]);
}

// ---------------- layernorm: fp32 in -> bf16 out ----------------
__global__ void ln_kernel(const float* __restrict__ x, const float* __restrict__ g,
                          const float* __restrict__ bb, unsigned short* __restrict__ out) {
    int tok = blockIdx.x, tid = threadIdx.x;
    const float4 v = ((const float4*)(x + (size_t)tok * Cz))[tid];
    float s = v.x + v.y + v.z + v.w;
    float sq = v.x * v.x + v.y * v.y + v.z * v.z + v.w * v.w;
    #pragma unroll
    for (int m = 1; m < 64; m <<= 1) { s += __shfl_xor(s, m); sq += __shfl_xor(sq, m); }
    __shared__ float red[8];
    int lane = tid & 63, wid = tid >> 6;
    if (!lane) { red[wid] = s; red[4 + wid] = sq; }
    __syncthreads();
    s = red[0] + red[1] + red[2] + red[3];
    sq = red[4] + red[5] + red[6] + red[7];
    float mu = s * (1.0f / Cz);
    float var = sq * (1.0f / Cz) - mu * mu;
    float rs = rsqrtf(var + 1e-5f);
    float4 gv = ((const float4*)g)[tid];
    float4 bv = ((const float4*)bb)[tid];
    short4v o;
    o[0] = f2bf((v.x - mu) * rs * gv.x + bv.x);
    o[1] = f2bf((v.y - mu) * rs * gv.y + bv.y);
    o[2] = f2bf((v.z - mu) * rs * gv.z + bv.z);
    o[3] = f2bf((v.w - mu) * rs * gv.w + bv.w);
    *(short4v*)(out + (size_t)tok * Cz + tid * 4) = o;
}

// ---------------- GEMM: C = A[M,K] @ Bt[N,K]^T, BK=64, bank-swizzled LDS ----------------
// LDS slot [row][s] (8-short segs) holds global seg (s ^ (row&7)); staging swizzles the
// GLOBAL source column (global_load_lds dest must stay base+lane*16B).
#define MODE_QKV 0
#define MODE_RESID 1
#define MODE_GELU 2

template <int MODE>
__launch_bounds__(256)
__global__ void gemm_bt(const unsigned short* __restrict__ A, const unsigned short* __restrict__ Bt,
                        int ld, int K, int N, const float* __restrict__ bias,
                        float* __restrict__ outf, unsigned short* __restrict__ outb,
                        const float* __restrict__ resid,
                        unsigned short* __restrict__ qo, unsigned short* __restrict__ ko,
                        unsigned short* __restrict__ vo) {
    __shared__ __align__(16) unsigned short As[128 * 64];
    __shared__ __align__(16) unsigned short Bs[128 * 64];
    const int tid = threadIdx.x;
    const int lane = tid & 63;
    const int quad = lane >> 4, l15 = lane & 15;
    const int wid = tid >> 6;
    const int m0 = blockIdx.y * 128, n0 = blockIdx.x * 128;
    const int wm = (wid >> 1) * 64, wn = (wid & 1) * 64;
    f32x4 acc[4][4] = {};

    // staging: 4 cp16/thread for A, 4 for B; row = wid*32 + j*8 + (lane>>3),
    // global col seg swizzled by row&7 = lane>>3
    const int srow = lane >> 3;                 // 0..7
    const int scol = ((lane & 7) ^ srow) * 8;   // swizzled global col
    const unsigned short* Ag[4];
    const unsigned short* Bg[4];
    unsigned short* lA[4];
    unsigned short* lB[4];
    #pragma unroll
    for (int j = 0; j < 4; j++) {
        const int row = wid * 32 + j * 8 + srow;
        Ag[j] = A + (size_t)(m0 + row) * ld + scol;
        Bg[j] = Bt + (size_t)(n0 + row) * ld + scol;
        lA[j] = &As[(wid * 4 + j) * 512 + lane * 8];
        lB[j] = &Bs[(wid * 4 + j) * 512 + lane * 8];
    }

    for (int k0 = 0; k0 < K; k0 += 64) {
        #pragma unroll
        for (int j = 0; j < 4; j++) async_cp16(Ag[j] + k0, lA[j]);
        #pragma unroll
        for (int j = 0; j < 4; j++) async_cp16(Bg[j] + k0, lB[j]);
        __syncthreads();
        #pragma unroll
        for (int ks = 0; ks < 2; ks++) {
            short8 af[4], bfr[4];
            #pragma unroll
            for (int i = 0; i < 4; i++) {
                const int ra = wm + i * 16 + l15;
                af[i] = *(const short8*)&As[ra * 64 + (((ks << 2) + quad) ^ (ra & 7)) * 8];
            }
            #pragma unroll
            for (int i = 0; i < 4; i++) {
                const int rb = wn + i * 16 + l15;
                bfr[i] = *(const short8*)&Bs[rb * 64 + (((ks << 2) + quad) ^ (rb & 7)) * 8];
            }
            #pragma unroll
            for (int mi = 0; mi < 4; mi++)
                #pragma unroll
                for (int ni = 0; ni < 4; ni++)
                    acc[mi][ni] = __builtin_amdgcn_mfma_f32_16x16x32_bf16(af[mi], bfr[ni], acc[mi][ni], 0, 0, 0);
        }
        __syncthreads();
    }

    #pragma unroll
    for (int ni = 0; ni < 4; ni++) {
        const int col = n0 + wn + ni * 16 + l15;
        const float bv = bias[col];
        #pragma unroll
        for (int mi = 0; mi < 4; mi++) {
            #pragma unroll
            for (int r = 0; r < 4; r++) {
                const int row = m0 + wm + mi * 16 + quad * 4 + r;
                float val = acc[mi][ni][r] + bv;
                if constexpr (MODE == MODE_QKV) {
                    int which = col >> 10, cc = col & 1023;
                    int hh = cc >> 6, dd = cc & 63;
                    int b_ = row >> 11, t = row & 2047;
                    if (which == 2) {
                        vo[((size_t)(b_ * Hz + hh) * Dz + dd) * Tz + t] = f2bf(val);
                    } else {
                        unsigned short* dst = which ? ko : qo;
                        dst[((size_t)(b_ * Hz + hh) * Tz + t) * Dz + dd] = f2bf(val);
                    }
                } else if constexpr (MODE == MODE_RESID) {
                    size_t idx = (size_t)row * N + col;
                    outf[idx] = val + resid[idx];
                } else {  // MODE_GELU, tanh-form
                    float c = val * (1.0f + 0.044715f * val * val);
                    float e = __expf(1.5957691216057308f * c);
                    float gz = val * e / (1.0f + e);
                    outb[(size_t)row * N + col] = f2bf(gz);
                }
            }
        }
    }
}

// ---------------- causal flash attention, bf16 MFMA ----------------
#define ATT_SC 0.18033688011112042f   // 0.125 * log2(e)
__launch_bounds__(256)
__global__ void attn_kernel(const unsigned short* __restrict__ qb, const unsigned short* __restrict__ kb,
                            const unsigned short* __restrict__ vt, unsigned short* __restrict__ y) {
    __shared__ __align__(16) unsigned short Klds[64 * 72];
    __shared__ __align__(16) unsigned short Vtl[64 * 72];
    __shared__ __align__(16) unsigned short Plds[4][16 * 72];
    const int tid = threadIdx.x;
    const int lane = tid & 63, wid = tid >> 6;
    const int quad = lane >> 4, l15 = lane & 15;
    const int bh = blockIdx.x & 63;
    const int qt = 15 - (int)(blockIdx.x >> 6);
    const size_t baseT = (size_t)bh * Tz;
    const size_t vbase = (size_t)bh * Dz;
    const int qb0 = qt * 128;

    short8 qf[2][2];
    {
        const unsigned short* q0p = qb + (baseT + qb0 + wid * 16 + l15) * Dz + quad * 8;
        qf[0][0] = *(const short8*)q0p;
        qf[0][1] = *(const short8*)(q0p + 32);
        const unsigned short* q1p = q0p + (size_t)64 * Dz;
        qf[1][0] = *(const short8*)q1p;
        qf[1][1] = *(const short8*)(q1p + 32);
    }

    f32x4 o[2][4] = {};
    float lsum[2][4] = {{0.f,0.f,0.f,0.f},{0.f,0.f,0.f,0.f}};

    const int krow = tid >> 3;
    const int kcol = (tid & 7) * 8;
    const int nchunk = 2 * qt + 2;

    for (int ci = 0; ci < nchunk; ci++) {
        const int k0 = ci * 64;
        *(short8*)&Klds[krow * 72 + kcol]        = *(const short8*)(kb + (baseT + k0 + krow) * Dz + kcol);
        *(short8*)&Klds[(krow + 32) * 72 + kcol] = *(const short8*)(kb + (baseT + k0 + krow + 32) * Dz + kcol);
        *(short8*)&Vtl[krow * 72 + kcol]         = *(const short8*)(vt + (vbase + krow) * Tz + k0 + kcol);
        *(short8*)&Vtl[(krow + 32) * 72 + kcol]  = *(const short8*)(vt + (vbase + krow + 32) * Tz + k0 + kcol);
        __syncthreads();

        #pragma unroll
        for (int t = 0; t < 2; t++) {
            if (t == 0 && ci == nchunk - 1) continue;
            const bool diag = (ci == nchunk - 2 + t);

            f32x4 s[4];
            #pragma unroll
            for (int c = 0; c < 4; c++) {
                short8 kf0 = *(const short8*)&Klds[(c * 16 + l15) * 72 + quad * 8];
                short8 kf1 = *(const short8*)&Klds[(c * 16 + l15) * 72 + 32 + quad * 8];
                f32x4 z = {};
                z = __builtin_amdgcn_mfma_f32_16x16x32_bf16(qf[t][0], kf0, z, 0, 0, 0);
                s[c] = __builtin_amdgcn_mfma_f32_16x16x32_bf16(qf[t][1], kf1, z, 0, 0, 0);
            }
            const int qr = qb0 + t * 64 + wid * 16 + quad * 4;
            #pragma unroll
            for (int c = 0; c < 4; c++)
                #pragma unroll
                for (int r = 0; r < 4; r++) {
                    float p = exp2f(s[c][r] * ATT_SC);
                    if (diag) {
                        int key = k0 + c * 16 + l15;
                        p = (key <= qr + r) ? p : 0.f;
                    }
                    s[c][r] = p;
                    lsum[t][r] += p;
                }
            unsigned short* P = Plds[wid];
            #pragma unroll
            for (int c = 0; c < 4; c++)
                #pragma unroll
                for (int r = 0; r < 4; r++)
                    P[(quad * 4 + r) * 72 + c * 16 + l15] = f2bf(s[c][r]);
            short8 pf0 = *(const short8*)&P[l15 * 72 + quad * 8];
            short8 pf1 = *(const short8*)&P[l15 * 72 + 32 + quad * 8];
            #pragma unroll
            for (int nc = 0; nc < 4; nc++) {
                short8 vf0 = *(const short8*)&Vtl[(nc * 16 + l15) * 72 + quad * 8];
                short8 vf1 = *(const short8*)&Vtl[(nc * 16 + l15) * 72 + 32 + quad * 8];
                o[t][nc] = __builtin_amdgcn_mfma_f32_16x16x32_bf16(pf0, vf0, o[t][nc], 0, 0, 0);
                o[t][nc] = __builtin_amdgcn_mfma_f32_16x16x32_bf16(pf1, vf1, o[t][nc], 0, 0, 0);
            }
        }
        __syncthreads();
    }

    const int b_ = bh >> 4, hh = bh & 15;
    #pragma unroll
    for (int t = 0; t < 2; t++)
        #pragma unroll
        for (int r = 0; r < 4; r++) {
            float ls = lsum[t][r];
            #pragma unroll
            for (int m = 1; m < 16; m <<= 1) ls += __shfl_xor(ls, m);
            float inv = 1.0f / ls;
            size_t tok = (size_t)qb0 + t * 64 + wid * 16 + quad * 4 + r;
            unsigned short* yr = y + ((size_t)b_ * Tz + tok) * Cz + hh * Dz;
            #pragma unroll
            for (int nc = 0; nc < 4; nc++)
                yr[nc * 16 + l15] = f2bf(o[t][nc][r] * inv);
        }
}

extern "C" void kernel_launch(void* const* d_in, const int* in_sizes, int n_in,
                              void* d_out, int out_size, void* d_ws, size_t ws_size,
                              hipStream_t stream) {
    const float* x    = (const float*)d_in[0];
    const float* ln1g = (const float*)d_in[1];
    const float* ln1b = (const float*)d_in[2];
    const float* Wqkv = (const float*)d_in[3];
    const float* bqkv = (const float*)d_in[4];
    const float* Wo   = (const float*)d_in[5];
    const float* bo   = (const float*)d_in[6];
    const float* ln2g = (const float*)d_in[7];
    const float* ln2b = (const float*)d_in[8];
    const float* Wfc  = (const float*)d_in[9];
    const float* bfc  = (const float*)d_in[10];
    const float* Wpr  = (const float*)d_in[11];
    const float* bpr  = (const float*)d_in[12];
    float* out = (float*)d_out;

    char* ws = (char*)d_ws;
    size_t off = 0;
    auto alloc = [&](size_t bytes) { void* p = ws + off; off += (bytes + 255) & ~(size_t)255; return p; };
    unsigned short* wqkv_t = (unsigned short*)alloc((size_t)3072 * 1024 * 2);
    unsigned short* wo_t   = (unsigned short*)alloc((size_t)1024 * 1024 * 2);
    unsigned short* wfc_t  = (unsigned short*)alloc((size_t)4096 * 1024 * 2);
    unsigned short* wpr_t  = (unsigned short*)alloc((size_t)1024 * 4096 * 2);
    unsigned short* h1     = (unsigned short*)alloc((size_t)MTOK * Cz * 2);
    unsigned short* qbuf   = (unsigned short*)alloc((size_t)MTOK * Cz * 2);
    unsigned short* kbuf   = (unsigned short*)alloc((size_t)MTOK * Cz * 2);
    unsigned short* vbuf   = (unsigned short*)alloc((size_t)MTOK * Cz * 2);
    unsigned short* ybuf   = (unsigned short*)alloc((size_t)MTOK * Cz * 2);
    float*          x1     = (float*)alloc((size_t)MTOK * Cz * 4);
    unsigned short* h2     = (unsigned short*)alloc((size_t)MTOK * Cz * 2);
    unsigned short* fbuf   = (unsigned short*)alloc((size_t)MTOK * 4096 * 2);

    dim3 tb(32, 8);
    transpose_w<<<dim3(3072 / 32, 1024 / 32), tb, 0, stream>>>(Wqkv, wqkv_t, 1024, 3072);
    transpose_w<<<dim3(1024 / 32, 1024 / 32), tb, 0, stream>>>(Wo, wo_t, 1024, 1024);
    transpose_w<<<dim3(4096 / 32, 1024 / 32), tb, 0, stream>>>(Wfc, wfc_t, 1024, 4096);
    transpose_w<<<dim3(1024 / 32, 4096 / 32), tb, 0, stream>>>(Wpr, wpr_t, 4096, 1024);

    ln_kernel<<<MTOK, 256, 0, stream>>>(x, ln1g, ln1b, h1);
    gemm_bt<MODE_QKV><<<dim3(24, 64), 256, 0, stream>>>(h1, wqkv_t, 1024, 1024, 3072, bqkv,
                                                        nullptr, nullptr, nullptr, qbuf, kbuf, vbuf);
    attn_kernel<<<1024, 256, 0, stream>>>(qbuf, kbuf, vbuf, ybuf);
    gemm_bt<MODE_RESID><<<dim3(8, 64), 256, 0, stream>>>(ybuf, wo_t, 1024, 1024, 1024, bo,
                                                         x1, nullptr, x, nullptr, nullptr, nullptr);
    ln_kernel<<<MTOK, 256, 0, stream>>>(x1, ln2g, ln2b, h2);
    gemm_bt<MODE_GELU><<<dim3(32, 64), 256, 0, stream>>>(h2, wfc_t, 1024, 1024, 4096, bfc,
                                                         nullptr, fbuf, nullptr, nullptr, nullptr, nullptr);
    gemm_bt<MODE_RESID><<<dim3(8, 64), 256, 0, stream>>>(fbuf, wpr_t, 4096, 4096, 1024, bpr,
                                                         out, nullptr, x1, nullptr, nullptr, nullptr);
}

// Round 6
// 528.353 us; speedup vs baseline: 1.2768x; 1.1151x over previous
//
#include <hip/hip_runtime.h>
#include <math.h>

#define Bz 4
#define Tz 2048
#define Cz 1024
#define Hz 16
#define Dz 64
#define MTOK (Bz*Tz)   // 8192

typedef __attribute__((ext_vector_type(8))) short short8;
typedef __attribute__((ext_vector_type(4))) short short4v;
typedef __attribute__((ext_vector_type(4))) float f32x4;

typedef unsigned int u32_g __attribute__((address_space(1)));
typedef unsigned int u32_l __attribute__((address_space(3)));

__device__ __forceinline__ unsigned short f2bf(float f) {
    unsigned int u = __float_as_uint(f);
    u += 0x7fffu + ((u >> 16) & 1u);
    return (unsigned short)(u >> 16);
}
__device__ __forceinline__ float bf2f(unsigned short h) {
    return __uint_as_float((unsigned int)h << 16);
}

__device__ __forceinline__ void async_cp16(const unsigned short* g, unsigned short* l) {
    __builtin_amdgcn_global_load_lds((const u32_g*)g, (u32_l*)l, 16, 0, 0);
}

// ---------------- weight transpose: W[K][N] f32 -> Wt[N][K] bf16 ----------------
__global__ void transpose_w(const float* __restrict__ W, unsigned short* __restrict__ Wt,
                            int K, int N) {
    __shared__ float tile[32][33];
    int n0 = blockIdx.x * 32, k0 = blockIdx.y * 32;
    int tx = threadIdx.x, ty = threadIdx.y;   // (32, 8)
    #pragma unroll
    for (int i = 0; i < 4; i++)
        tile[ty + i * 8][tx] = W[(size_t)(k0 + ty + i * 8) * N + n0 + tx];
    __syncthreads();
    #pragma unroll
    for (int i = 0; i < 4; i++)
        Wt[(size_t)(n0 + ty + i * 8) * K + k0 + tx] = f2bf(tile[tx][ty + i * 8]);
}

// ---------------- layernorm: fp32 in -> bf16 out ----------------
__global__ void ln_kernel(const float* __restrict__ x, const float* __restrict__ g,
                          const float* __restrict__ bb, unsigned short* __restrict__ out) {
    int tok = blockIdx.x, tid = threadIdx.x;
    const float4 v = ((const float4*)(x + (size_t)tok * Cz))[tid];
    float s = v.x + v.y + v.z + v.w;
    float sq = v.x * v.x + v.y * v.y + v.z * v.z + v.w * v.w;
    #pragma unroll
    for (int m = 1; m < 64; m <<= 1) { s += __shfl_xor(s, m); sq += __shfl_xor(sq, m); }
    __shared__ float red[8];
    int lane = tid & 63, wid = tid >> 6;
    if (!lane) { red[wid] = s; red[4 + wid] = sq; }
    __syncthreads();
    s = red[0] + red[1] + red[2] + red[3];
    sq = red[4] + red[5] + red[6] + red[7];
    float mu = s * (1.0f / Cz);
    float var = sq * (1.0f / Cz) - mu * mu;
    float rs = rsqrtf(var + 1e-5f);
    float4 gv = ((const float4*)g)[tid];
    float4 bv = ((const float4*)bb)[tid];
    short4v o;
    o[0] = f2bf((v.x - mu) * rs * gv.x + bv.x);
    o[1] = f2bf((v.y - mu) * rs * gv.y + bv.y);
    o[2] = f2bf((v.z - mu) * rs * gv.z + bv.z);
    o[3] = f2bf((v.w - mu) * rs * gv.w + bv.w);
    *(short4v*)(out + (size_t)tok * Cz + tid * 4) = o;
}

// ---------------- GEMM: C = A[M,K] @ Bt[N,K]^T, BK=64, bank-swizzled LDS ----------------
// 1D grid, XCD-aware remap: XCD (id&7) owns m-tiles [(id&7)*8, +8) x all n-tiles,
// so A-tiles are fetched once per XCD (L2-resident per k-slice).
#define MODE_QKV 0
#define MODE_RESID 1
#define MODE_GELU 2

template <int MODE>
__launch_bounds__(256)
__global__ void gemm_bt(const unsigned short* __restrict__ A, const unsigned short* __restrict__ Bt,
                        int ld, int K, int N, const float* __restrict__ bias,
                        float* __restrict__ outf, unsigned short* __restrict__ outb,
                        const float* __restrict__ resid,
                        unsigned short* __restrict__ qo, unsigned short* __restrict__ ko,
                        unsigned short* __restrict__ vo) {
    __shared__ __align__(16) unsigned short As[128 * 64];
    __shared__ __align__(16) unsigned short Bs[128 * 64];
    const int tid = threadIdx.x;
    const int lane = tid & 63;
    const int quad = lane >> 4, l15 = lane & 15;
    const int wid = tid >> 6;
    const int id = blockIdx.x;
    const int m0 = ((id & 7) * 8 + ((id >> 3) & 7)) * 128;
    const int n0 = (id >> 6) * 128;
    const int wm = (wid >> 1) * 64, wn = (wid & 1) * 64;
    f32x4 acc[4][4] = {};

    // staging: 4 cp16/thread for A, 4 for B; row = wid*32 + j*8 + (lane>>3),
    // global col seg swizzled by row&7 = lane>>3
    const int srow = lane >> 3;                 // 0..7
    const int scol = ((lane & 7) ^ srow) * 8;   // swizzled global col
    const unsigned short* Ag[4];
    const unsigned short* Bg[4];
    unsigned short* lA[4];
    unsigned short* lB[4];
    #pragma unroll
    for (int j = 0; j < 4; j++) {
        const int row = wid * 32 + j * 8 + srow;
        Ag[j] = A + (size_t)(m0 + row) * ld + scol;
        Bg[j] = Bt + (size_t)(n0 + row) * ld + scol;
        lA[j] = &As[(wid * 4 + j) * 512 + lane * 8];
        lB[j] = &Bs[(wid * 4 + j) * 512 + lane * 8];
    }

    for (int k0 = 0; k0 < K; k0 += 64) {
        #pragma unroll
        for (int j = 0; j < 4; j++) async_cp16(Ag[j] + k0, lA[j]);
        #pragma unroll
        for (int j = 0; j < 4; j++) async_cp16(Bg[j] + k0, lB[j]);
        __syncthreads();
        #pragma unroll
        for (int ks = 0; ks < 2; ks++) {
            short8 af[4], bfr[4];
            #pragma unroll
            for (int i = 0; i < 4; i++) {
                const int ra = wm + i * 16 + l15;
                af[i] = *(const short8*)&As[ra * 64 + (((ks << 2) + quad) ^ (ra & 7)) * 8];
            }
            #pragma unroll
            for (int i = 0; i < 4; i++) {
                const int rb = wn + i * 16 + l15;
                bfr[i] = *(const short8*)&Bs[rb * 64 + (((ks << 2) + quad) ^ (rb & 7)) * 8];
            }
            #pragma unroll
            for (int mi = 0; mi < 4; mi++)
                #pragma unroll
                for (int ni = 0; ni < 4; ni++)
                    acc[mi][ni] = __builtin_amdgcn_mfma_f32_16x16x32_bf16(af[mi], bfr[ni], acc[mi][ni], 0, 0, 0);
        }
        __syncthreads();
    }

    #pragma unroll
    for (int ni = 0; ni < 4; ni++) {
        const int col = n0 + wn + ni * 16 + l15;
        const float bv = bias[col];
        #pragma unroll
        for (int mi = 0; mi < 4; mi++) {
            #pragma unroll
            for (int r = 0; r < 4; r++) {
                const int row = m0 + wm + mi * 16 + quad * 4 + r;
                float val = acc[mi][ni][r] + bv;
                if constexpr (MODE == MODE_QKV) {
                    int which = col >> 10, cc = col & 1023;
                    int hh = cc >> 6, dd = cc & 63;
                    int b_ = row >> 11, t = row & 2047;
                    if (which == 2) {
                        vo[((size_t)(b_ * Hz + hh) * Dz + dd) * Tz + t] = f2bf(val);
                    } else {
                        unsigned short* dst = which ? ko : qo;
                        dst[((size_t)(b_ * Hz + hh) * Tz + t) * Dz + dd] = f2bf(val);
                    }
                } else if constexpr (MODE == MODE_RESID) {
                    size_t idx = (size_t)row * N + col;
                    outf[idx] = val + resid[idx];
                } else {  // MODE_GELU, tanh-form
                    float c = val * (1.0f + 0.044715f * val * val);
                    float e = __expf(1.5957691216057308f * c);
                    float gz = val * e / (1.0f + e);
                    outb[(size_t)row * N + col] = f2bf(gz);
                }
            }
        }
    }
}

// ---------------- causal flash attention, bf16 MFMA ----------------
// K/V staged via global_load_lds into unpadded stride-64 LDS with xor-column
// swizzle (slot [row][s] holds global seg s^(row&7)) — 0-conflict pattern.
#define ATT_SC 0.18033688011112042f   // 0.125 * log2(e)
__launch_bounds__(256)
__global__ void attn_kernel(const unsigned short* __restrict__ qb, const unsigned short* __restrict__ kb,
                            const unsigned short* __restrict__ vt, unsigned short* __restrict__ y) {
    __shared__ __align__(16) unsigned short Klds[64 * 64];
    __shared__ __align__(16) unsigned short Vtl[64 * 64];
    __shared__ __align__(16) unsigned short Plds[4][16 * 72];
    const int tid = threadIdx.x;
    const int lane = tid & 63, wid = tid >> 6;
    const int quad = lane >> 4, l15 = lane & 15;
    const int bh = blockIdx.x & 63;
    const int qt = 15 - (int)(blockIdx.x >> 6);
    const size_t baseT = (size_t)bh * Tz;
    const size_t vbase = (size_t)bh * Dz;
    const int qb0 = qt * 128;

    short8 qf[2][2];
    {
        const unsigned short* q0p = qb + (baseT + qb0 + wid * 16 + l15) * Dz + quad * 8;
        qf[0][0] = *(const short8*)q0p;
        qf[0][1] = *(const short8*)(q0p + 32);
        const unsigned short* q1p = q0p + (size_t)64 * Dz;
        qf[1][0] = *(const short8*)q1p;
        qf[1][1] = *(const short8*)(q1p + 32);
    }

    f32x4 o[2][4] = {};
    float lsum[2][4] = {{0.f,0.f,0.f,0.f},{0.f,0.f,0.f,0.f}};

    // async staging pointers: row = wid*8 + (lane>>3) (and +32), swizzled global col
    const int srow = lane >> 3;
    const int swz = ((lane & 7) ^ srow) * 8;
    const unsigned short* kg0 = kb + (baseT + wid * 8 + srow) * Dz + swz;
    const unsigned short* kg1 = kg0 + (size_t)32 * Dz;
    const unsigned short* vg0 = vt + (vbase + wid * 8 + srow) * Tz + swz;
    const unsigned short* vg1 = vg0 + (size_t)32 * Tz;
    unsigned short* kl0 = &Klds[wid * 512 + lane * 8];
    unsigned short* kl1 = kl0 + 2048;
    unsigned short* vl0 = &Vtl[wid * 512 + lane * 8];
    unsigned short* vl1 = vl0 + 2048;

    const int nchunk = 2 * qt + 2;

    for (int ci = 0; ci < nchunk; ci++) {
        const int k0 = ci * 64;
        async_cp16(kg0 + (size_t)k0 * Dz, kl0);
        async_cp16(kg1 + (size_t)k0 * Dz, kl1);
        async_cp16(vg0 + k0, vl0);
        async_cp16(vg1 + k0, vl1);
        __syncthreads();

        #pragma unroll
        for (int t = 0; t < 2; t++) {
            if (t == 0 && ci == nchunk - 1) continue;
            const bool diag = (ci == nchunk - 2 + t);

            f32x4 s[4];
            #pragma unroll
            for (int c = 0; c < 4; c++) {
                const int rk = c * 16 + l15;
                short8 kf0 = *(const short8*)&Klds[rk * 64 + ((quad ^ (rk & 7)) * 8)];
                short8 kf1 = *(const short8*)&Klds[rk * 64 + (((quad + 4) ^ (rk & 7)) * 8)];
                f32x4 z = {};
                z = __builtin_amdgcn_mfma_f32_16x16x32_bf16(qf[t][0], kf0, z, 0, 0, 0);
                s[c] = __builtin_amdgcn_mfma_f32_16x16x32_bf16(qf[t][1], kf1, z, 0, 0, 0);
            }
            const int qr = qb0 + t * 64 + wid * 16 + quad * 4;
            #pragma unroll
            for (int c = 0; c < 4; c++)
                #pragma unroll
                for (int r = 0; r < 4; r++) {
                    float p = exp2f(s[c][r] * ATT_SC);
                    if (diag) {
                        int key = k0 + c * 16 + l15;
                        p = (key <= qr + r) ? p : 0.f;
                    }
                    s[c][r] = p;
                    lsum[t][r] += p;
                }
            unsigned short* P = Plds[wid];
            #pragma unroll
            for (int c = 0; c < 4; c++)
                #pragma unroll
                for (int r = 0; r < 4; r++)
                    P[(quad * 4 + r) * 72 + c * 16 + l15] = f2bf(s[c][r]);
            short8 pf0 = *(const short8*)&P[l15 * 72 + quad * 8];
            short8 pf1 = *(const short8*)&P[l15 * 72 + 32 + quad * 8];
            #pragma unroll
            for (int nc = 0; nc < 4; nc++) {
                const int rv = nc * 16 + l15;
                short8 vf0 = *(const short8*)&Vtl[rv * 64 + ((quad ^ (rv & 7)) * 8)];
                short8 vf1 = *(const short8*)&Vtl[rv * 64 + (((quad + 4) ^ (rv & 7)) * 8)];
                o[t][nc] = __builtin_amdgcn_mfma_f32_16x16x32_bf16(pf0, vf0, o[t][nc], 0, 0, 0);
                o[t][nc] = __builtin_amdgcn_mfma_f32_16x16x32_bf16(pf1, vf1, o[t][nc], 0, 0, 0);
            }
        }
        __syncthreads();
    }

    const int b_ = bh >> 4, hh = bh & 15;
    #pragma unroll
    for (int t = 0; t < 2; t++)
        #pragma unroll
        for (int r = 0; r < 4; r++) {
            float ls = lsum[t][r];
            #pragma unroll
            for (int m = 1; m < 16; m <<= 1) ls += __shfl_xor(ls, m);
            float inv = 1.0f / ls;
            size_t tok = (size_t)qb0 + t * 64 + wid * 16 + quad * 4 + r;
            unsigned short* yr = y + ((size_t)b_ * Tz + tok) * Cz + hh * Dz;
            #pragma unroll
            for (int nc = 0; nc < 4; nc++)
                yr[nc * 16 + l15] = f2bf(o[t][nc][r] * inv);
        }
}

extern "C" void kernel_launch(void* const* d_in, const int* in_sizes, int n_in,
                              void* d_out, int out_size, void* d_ws, size_t ws_size,
                              hipStream_t stream) {
    const float* x    = (const float*)d_in[0];
    const float* ln1g = (const float*)d_in[1];
    const float* ln1b = (const float*)d_in[2];
    const float* Wqkv = (const float*)d_in[3];
    const float* bqkv = (const float*)d_in[4];
    const float* Wo   = (const float*)d_in[5];
    const float* bo   = (const float*)d_in[6];
    const float* ln2g = (const float*)d_in[7];
    const float* ln2b = (const float*)d_in[8];
    const float* Wfc  = (const float*)d_in[9];
    const float* bfc  = (const float*)d_in[10];
    const float* Wpr  = (const float*)d_in[11];
    const float* bpr  = (const float*)d_in[12];
    float* out = (float*)d_out;

    char* ws = (char*)d_ws;
    size_t off = 0;
    auto alloc = [&](size_t bytes) { void* p = ws + off; off += (bytes + 255) & ~(size_t)255; return p; };
    unsigned short* wqkv_t = (unsigned short*)alloc((size_t)3072 * 1024 * 2);
    unsigned short* wo_t   = (unsigned short*)alloc((size_t)1024 * 1024 * 2);
    unsigned short* wfc_t  = (unsigned short*)alloc((size_t)4096 * 1024 * 2);
    unsigned short* wpr_t  = (unsigned short*)alloc((size_t)1024 * 4096 * 2);
    unsigned short* h1     = (unsigned short*)alloc((size_t)MTOK * Cz * 2);
    unsigned short* qbuf   = (unsigned short*)alloc((size_t)MTOK * Cz * 2);
    unsigned short* kbuf   = (unsigned short*)alloc((size_t)MTOK * Cz * 2);
    unsigned short* vbuf   = (unsigned short*)alloc((size_t)MTOK * Cz * 2);
    unsigned short* ybuf   = (unsigned short*)alloc((size_t)MTOK * Cz * 2);
    float*          x1     = (float*)alloc((size_t)MTOK * Cz * 4);
    unsigned short* h2     = (unsigned short*)alloc((size_t)MTOK * Cz * 2);
    unsigned short* fbuf   = (unsigned short*)alloc((size_t)MTOK * 4096 * 2);

    dim3 tb(32, 8);
    transpose_w<<<dim3(3072 / 32, 1024 / 32), tb, 0, stream>>>(Wqkv, wqkv_t, 1024, 3072);
    transpose_w<<<dim3(1024 / 32, 1024 / 32), tb, 0, stream>>>(Wo, wo_t, 1024, 1024);
    transpose_w<<<dim3(4096 / 32, 1024 / 32), tb, 0, stream>>>(Wfc, wfc_t, 1024, 4096);
    transpose_w<<<dim3(1024 / 32, 4096 / 32), tb, 0, stream>>>(Wpr, wpr_t, 4096, 1024);

    ln_kernel<<<MTOK, 256, 0, stream>>>(x, ln1g, ln1b, h1);
    gemm_bt<MODE_QKV><<<64 * 24, 256, 0, stream>>>(h1, wqkv_t, 1024, 1024, 3072, bqkv,
                                                   nullptr, nullptr, nullptr, qbuf, kbuf, vbuf);
    attn_kernel<<<1024, 256, 0, stream>>>(qbuf, kbuf, vbuf, ybuf);
    gemm_bt<MODE_RESID><<<64 * 8, 256, 0, stream>>>(ybuf, wo_t, 1024, 1024, 1024, bo,
                                                    x1, nullptr, x, nullptr, nullptr, nullptr);
    ln_kernel<<<MTOK, 256, 0, stream>>>(x1, ln2g, ln2b, h2);
    gemm_bt<MODE_GELU><<<64 * 32, 256, 0, stream>>>(h2, wfc_t, 1024, 1024, 4096, bfc,
                                                    nullptr, fbuf, nullptr, nullptr, nullptr, nullptr);
    gemm_bt<MODE_RESID><<<64 * 8, 256, 0, stream>>>(fbuf, wpr_t, 4096, 4096, 1024, bpr,
                                                    out, nullptr, x1, nullptr, nullptr, nullptr);
}